// Round 11
// baseline (109.693 us; speedup 1.0000x reference)
//
#include <hip/hip_runtime.h>
#include <hip/hip_bf16.h>

// Problem constants (B=2, S=2048, D=512, H=8, hd=64)
constexpr int Bc = 2, Sc = 2048, Dc = 512, Hc = 8, HDc = 64;
constexpr int Mtot = Bc * Sc;    // 4096
constexpr size_t HEADMAT = (size_t)Bc * Hc * Sc * HDc;  // 2M elems
// softmax in log2 domain: e2 = s*(0.125*log2e) - 10000*log2e*masks
constexpr float SC2  = 0.18033688011112042f;   // 0.125 * log2(e)
constexpr float NEG2 = 14426.950408889634f;    // 10000 * log2(e)

typedef __attribute__((ext_vector_type(8))) short          short8;
typedef __attribute__((ext_vector_type(8))) unsigned short ushort8;
typedef __attribute__((ext_vector_type(4))) float          f32x4;

#define MFMA16 __builtin_amdgcn_mfma_f32_16x16x32_bf16

static __device__ __forceinline__ unsigned short f32_to_bf16_bits(float f) {
    unsigned int u = __builtin_bit_cast(unsigned int, f);
    unsigned int r = u + 0x7FFFu + ((u >> 16) & 1u);   // RNE
    return (unsigned short)(r >> 16);
}

// ---------------------------------------------------------------------------
// x f32 -> bf16 (row-major [M][512] unchanged layout)
// ---------------------------------------------------------------------------
__global__ __launch_bounds__(256)
void convert_x(const float* __restrict__ x, unsigned short* __restrict__ Xb, int n)
{
    const int i = (blockIdx.x * 256 + threadIdx.x) * 4;
    if (i >= n) return;
    const float4 v = *(const float4*)(x + i);
    ushort4 o;
    o.x = f32_to_bf16_bits(v.x);
    o.y = f32_to_bf16_bits(v.y);
    o.z = f32_to_bf16_bits(v.z);
    o.w = f32_to_bf16_bits(v.w);
    *(ushort4*)(Xb + i) = o;
}

// ---------------------------------------------------------------------------
// W [512][512] f32 -> W^T [512][512] bf16, z = {Wq,Wk,Wv,Wo}. 64x64 LDS tile.
// ---------------------------------------------------------------------------
__global__ __launch_bounds__(256)
void transpose_w(const float* __restrict__ W0, const float* __restrict__ W1,
                 const float* __restrict__ W2, const float* __restrict__ W3,
                 unsigned short* __restrict__ Wt)
{
    __shared__ float T[64][65];
    const int z = blockIdx.z;
    const float* Wp = (z == 0) ? W0 : (z == 1) ? W1 : (z == 2) ? W2 : W3;
    unsigned short* Op = Wt + (size_t)z * 512 * 512;

    const int kt = blockIdx.y * 64, nt = blockIdx.x * 64;
    const int t = threadIdx.x;
    const int r  = t >> 2, c4 = (t & 3) * 16;

    #pragma unroll
    for (int i = 0; i < 4; ++i) {
        const float4 v = *(const float4*)(Wp + (size_t)(kt + r) * 512 + nt + c4 + 4 * i);
        T[r][c4 + 4*i + 0] = v.x;
        T[r][c4 + 4*i + 1] = v.y;
        T[r][c4 + 4*i + 2] = v.z;
        T[r][c4 + 4*i + 3] = v.w;
    }
    __syncthreads();

    const int n = t >> 2, k4 = (t & 3) * 16;
    #pragma unroll
    for (int i = 0; i < 4; ++i) {
        ushort4 o;
        o.x = f32_to_bf16_bits(T[k4 + 4*i + 0][n]);
        o.y = f32_to_bf16_bits(T[k4 + 4*i + 1][n]);
        o.z = f32_to_bf16_bits(T[k4 + 4*i + 2][n]);
        o.w = f32_to_bf16_bits(T[k4 + 4*i + 3][n]);
        *(ushort4*)(Op + (size_t)(nt + n) * 512 + kt + k4 + 4 * i) = o;
    }
}

// ---------------------------------------------------------------------------
// Tiled bf16 MFMA GEMM (unchanged from R9 -- verified).
// ---------------------------------------------------------------------------
template<bool HEADOUT>
__global__ __launch_bounds__(256)
void gemm_tile(const unsigned short* __restrict__ Xb,
               const unsigned short* __restrict__ Wt,
               const float* __restrict__ b0, const float* __restrict__ b1,
               const float* __restrict__ b2,
               unsigned short* __restrict__ Hout,
               float* __restrict__ Yf)
{
    __shared__ short As[128 * 32];   // [m][k] 8KB
    __shared__ short Bs[64 * 32];    // [n][k] 4KB

    const int lane = threadIdx.x & 63, wave = threadIdx.x >> 6;
    const int c = lane & 15, g = lane >> 4;
    const int wr = wave >> 1, wc = wave & 1;
    const int z = blockIdx.z;
    const unsigned short* Wp = Wt + (size_t)z * 512 * 512;
    const float* bp = (z == 0) ? b0 : (z == 1) ? b1 : b2;
    const int bm = blockIdx.y * 128;
    const int bn = blockIdx.x * 64;

    const int srow = lane >> 2;
    const int scol = (lane & 3) * 8;

    f32x4 acc[4][2] = {};

    for (int k0 = 0; k0 < 512; k0 += 32) {
        __syncthreads();
        #pragma unroll
        for (int i = 0; i < 2; ++i) {
            const int row = (wave * 2 + i) * 16 + srow;
            const short8 v = *(const short8*)(Xb + (size_t)(bm + row) * 512 + k0 + scol);
            *(short8*)(&As[row * 32 + scol]) = v;
        }
        {
            const int row = wave * 16 + srow;
            const short8 v = *(const short8*)(Wp + (size_t)(bn + row) * 512 + k0 + scol);
            *(short8*)(&Bs[row * 32 + scol]) = v;
        }
        __syncthreads();

        short8 a[4], bfr[2];
        #pragma unroll
        for (int mi = 0; mi < 4; ++mi)
            a[mi] = *(const short8*)(&As[(wr * 64 + mi * 16 + c) * 32 + g * 8]);
        #pragma unroll
        for (int ni = 0; ni < 2; ++ni)
            bfr[ni] = *(const short8*)(&Bs[(wc * 32 + ni * 16 + c) * 32 + g * 8]);
        #pragma unroll
        for (int mi = 0; mi < 4; ++mi)
            #pragma unroll
            for (int ni = 0; ni < 2; ++ni)
                acc[mi][ni] = MFMA16(a[mi], bfr[ni], acc[mi][ni], 0, 0, 0);
    }

    #pragma unroll
    for (int mi = 0; mi < 4; ++mi) {
        #pragma unroll
        for (int ni = 0; ni < 2; ++ni) {
            const int n = bn + wc * 32 + ni * 16 + c;
            const float bias = bp[n];
            float v[4];
            #pragma unroll
            for (int r = 0; r < 4; ++r)
                v[r] = fmaxf(acc[mi][ni][r] + bias, 0.0f);
            const int mbase = bm + wr * 64 + mi * 16 + 4 * g;
            if constexpr (HEADOUT) {
                const int bb = mbase >> 11, ss = mbase & 2047;
                const int hh = n >> 6, hd = n & 63;
                #pragma unroll
                for (int r = 0; r < 4; ++r)
                    Hout[(size_t)z * HEADMAT +
                         (((size_t)(bb * Hc + hh) * Sc + ss + r) * HDc + hd)] =
                        f32_to_bf16_bits(v[r]);
            } else {
                #pragma unroll
                for (int r = 0; r < 4; ++r)
                    Yf[(size_t)(mbase + r) * 512 + n] = v[r];
            }
        }
    }
}

// ---------------------------------------------------------------------------
// Split-K MFMA flash attention, v7 (= R9-verified core + 2 q-tiles/block).
// Block = 32 q-rows (two 16-row q-tiles A/B) of one (b,h); 4 waves take
// balanced contiguous chunks of 32-key tiles. K-frags / V-staging / V-reads /
// mask loads are SHARED between the two q-tiles -> 16 MFMA per 32-key iter.
// - V head-major; staged per-wave into PRIVATE LDS [32][72] via coalesced
//   16B loads issued early (R7/R9-verified gather path; tr-read reverted).
// - Softmax in exp2 domain (constants folded); defer-rescale via __any.
// - Causal compares skipped for fully-past tiles (k0+31 <= q0).
// - Combine partials in LDS overlay; empty chunks weight exactly 0.0f.
// ---------------------------------------------------------------------------
__global__ __launch_bounds__(256)
void attn_mfma(const short* __restrict__ Qh, const short* __restrict__ Kh,
               const short* __restrict__ Vh, const int* __restrict__ mask,
               unsigned short* __restrict__ Ob)
{
    // per-wave 9216B region: loop = V stage [32][72] bf16 (4608B);
    // combine overlay = Lacc[32][68] f32 (8704B) + m[32],l[32] (256B)
    __shared__ __align__(16) char smem[4 * 9216];

    const int lane = threadIdx.x & 63;
    const int wave = threadIdx.x >> 6;
    const int bid  = blockIdx.x;                    // 1024 blocks
    const int swz  = (bid & 7) * 128 + (bid >> 3);  // bijective, XCD-chunked
    const int qt   = swz & 63;
    const int h    = (swz >> 6) & 7;
    const int b    = swz >> 9;
    const int q0   = qt * 32;
    const int c    = lane & 15;
    const int g    = lane >> 4;

    char*  wbase = smem + wave * 9216;
    short* vst   = (short*)wbase;            // [32][72]
    float* Lacc  = (float*)wbase;            // overlay [32][68]
    float* Lml   = (float*)(wbase + 8704);   // overlay m[32], l[32]

    const size_t headoff = (size_t)(b * Hc + h) * Sc * HDc;
    const short* Qp = Qh + headoff;
    const short* Kp = Kh + headoff;
    const short* Vp = Vh + headoff;
    const int* mb = mask + b * Sc;

    // first unmasked key (block-uniform)
    int fb = Sc;
    for (int base = 0; base < Sc; base += 64) {
        unsigned long long bal = __ballot(mb[base + lane] != 0);
        if (bal) { fb = base + (__ffsll(bal) - 1); break; }
    }
    const int kmax = (fb <= q0) ? (q0 + 32) : Sc;
    const int kend = (kmax + 31) & ~31;
    const int nT   = kend >> 5;
    const int tpw  = (nT + 3) >> 2;
    const int kbeg = wave * tpw * 32;
    const int kfin = min(kend, kbeg + tpw * 32);

    const short8 qa0 = *(const short8*)(Qp + (size_t)(q0 + c) * HDc + g * 8);
    const short8 qa1 = *(const short8*)(Qp + (size_t)(q0 + c) * HDc + 32 + g * 8);
    const short8 qb0 = *(const short8*)(Qp + (size_t)(q0 + 16 + c) * HDc + g * 8);
    const short8 qb1 = *(const short8*)(Qp + (size_t)(q0 + 16 + c) * HDc + 32 + g * 8);

    f32x4 accA[4] = {{0,0,0,0},{0,0,0,0},{0,0,0,0},{0,0,0,0}};
    f32x4 accB[4] = {{0,0,0,0},{0,0,0,0},{0,0,0,0},{0,0,0,0}};
    float mA = -1e30f, lA = 0.f, mB = -1e30f, lB = 0.f;

    const int vrow = lane >> 1;            // 0..31
    const int vcol = (lane & 1) * 32;      // 0 or 32

    for (int k0 = kbeg; k0 < kfin; k0 += 32) {
        // --- V global loads issued early (hide under QK^T + softmax)
        const short* vsrc = Vp + (size_t)(k0 + vrow) * HDc + vcol;
        const ushort8 vr0 = *(const ushort8*)(vsrc + 0);
        const ushort8 vr1 = *(const ushort8*)(vsrc + 8);
        const ushort8 vr2 = *(const ushort8*)(vsrc + 16);
        const ushort8 vr3 = *(const ushort8*)(vsrc + 24);

        // --- K fragments + QK^T (K shared between q-tiles)
        const short8 kf0a = *(const short8*)(Kp + (size_t)(k0 + c) * HDc + g * 8);
        const short8 kf0b = *(const short8*)(Kp + (size_t)(k0 + c) * HDc + 32 + g * 8);
        const short8 kf1a = *(const short8*)(Kp + (size_t)(k0 + 16 + c) * HDc + g * 8);
        const short8 kf1b = *(const short8*)(Kp + (size_t)(k0 + 16 + c) * HDc + 32 + g * 8);

        f32x4 sa0 = {0,0,0,0}, sa1 = {0,0,0,0};
        f32x4 sb0 = {0,0,0,0}, sb1 = {0,0,0,0};
        sa0 = MFMA16(kf0a, qa0, sa0, 0, 0, 0);
        sa0 = MFMA16(kf0b, qa1, sa0, 0, 0, 0);
        sa1 = MFMA16(kf1a, qa0, sa1, 0, 0, 0);
        sa1 = MFMA16(kf1b, qa1, sa1, 0, 0, 0);
        sb0 = MFMA16(kf0a, qb0, sb0, 0, 0, 0);
        sb0 = MFMA16(kf0b, qb1, sb0, 0, 0, 0);
        sb1 = MFMA16(kf1a, qb0, sb1, 0, 0, 0);
        sb1 = MFMA16(kf1b, qb1, sb1, 0, 0, 0);

        const int4 mka = *(const int4*)(mb + k0 + 4 * g);
        const int4 mkb = *(const int4*)(mb + k0 + 16 + 4 * g);
        const int mia[4] = {mka.x, mka.y, mka.z, mka.w};
        const int mib[4] = {mkb.x, mkb.y, mkb.z, mkb.w};

        float eA[8], eB[8];
        float tA = -1e30f, tB = -1e30f;
        if (k0 + 31 > q0) {   // causal-affected tile (wave-uniform)
            #pragma unroll
            for (int r = 0; r < 4; ++r) {
                const int ka = k0 + 4 * g + r;
                const int kb = k0 + 16 + 4 * g + r;
                float e0 = sa0[r] * SC2; if (ka > q0 + c)      e0 -= NEG2;
                float e1 = sa1[r] * SC2; if (kb > q0 + c)      e1 -= NEG2;
                float e2 = sb0[r] * SC2; if (ka > q0 + 16 + c) e2 -= NEG2;
                float e3 = sb1[r] * SC2; if (kb > q0 + 16 + c) e3 -= NEG2;
                if (mia[r] == 0) { e0 -= NEG2; e2 -= NEG2; }
                if (mib[r] == 0) { e1 -= NEG2; e3 -= NEG2; }
                eA[r] = e0; eA[4 + r] = e1; tA = fmaxf(tA, fmaxf(e0, e1));
                eB[r] = e2; eB[4 + r] = e3; tB = fmaxf(tB, fmaxf(e2, e3));
            }
        } else {              // fully-past tile: no causal compares
            #pragma unroll
            for (int r = 0; r < 4; ++r) {
                float e0 = sa0[r] * SC2;
                float e1 = sa1[r] * SC2;
                float e2 = sb0[r] * SC2;
                float e3 = sb1[r] * SC2;
                if (mia[r] == 0) { e0 -= NEG2; e2 -= NEG2; }
                if (mib[r] == 0) { e1 -= NEG2; e3 -= NEG2; }
                eA[r] = e0; eA[4 + r] = e1; tA = fmaxf(tA, fmaxf(e0, e1));
                eB[r] = e2; eB[4 + r] = e3; tB = fmaxf(tB, fmaxf(e2, e3));
            }
        }
        tA = fmaxf(tA, __shfl_xor(tA, 16));
        tB = fmaxf(tB, __shfl_xor(tB, 16));
        tA = fmaxf(tA, __shfl_xor(tA, 32));
        tB = fmaxf(tB, __shfl_xor(tB, 32));

        if (__any(tA > mA)) {
            const float mn = fmaxf(mA, tA);
            const float corr = __builtin_exp2f(mA - mn);
            mA = mn; lA *= corr;
            float cq[4];
            #pragma unroll
            for (int r = 0; r < 4; ++r) cq[r] = __shfl(corr, 4 * g + r);
            #pragma unroll
            for (int t = 0; t < 4; ++t)
                #pragma unroll
                for (int r = 0; r < 4; ++r) accA[t][r] *= cq[r];
        }
        if (__any(tB > mB)) {
            const float mn = fmaxf(mB, tB);
            const float corr = __builtin_exp2f(mB - mn);
            mB = mn; lB *= corr;
            float cq[4];
            #pragma unroll
            for (int r = 0; r < 4; ++r) cq[r] = __shfl(corr, 4 * g + r);
            #pragma unroll
            for (int t = 0; t < 4; ++t)
                #pragma unroll
                for (int r = 0; r < 4; ++r) accB[t][r] *= cq[r];
        }

        float pA[8], pB[8], psA = 0.f, psB = 0.f;
        #pragma unroll
        for (int j = 0; j < 8; ++j) {
            pA[j] = __builtin_exp2f(eA[j] - mA); psA += pA[j];
            pB[j] = __builtin_exp2f(eB[j] - mB); psB += pB[j];
        }
        lA += psA; lB += psB;

        short8 pfa, pfb;
        #pragma unroll
        for (int j = 0; j < 8; ++j) {
            pfa[j] = (short)f32_to_bf16_bits(pA[j]);
            pfb[j] = (short)f32_to_bf16_bits(pB[j]);
        }

        // --- V regs -> private LDS (no barrier; wave-private region)
        short* vdst = vst + vrow * 72 + vcol;
        *(ushort8*)(vdst + 0)  = vr0;
        *(ushort8*)(vdst + 8)  = vr1;
        *(ushort8*)(vdst + 16) = vr2;
        *(ushort8*)(vdst + 24) = vr3;

        // --- PV from LDS (verified gather path), V frags shared A/B
        #pragma unroll
        for (int t = 0; t < 4; ++t) {
            short8 vf;
            #pragma unroll
            for (int j = 0; j < 4; ++j) {
                vf[j]     = vst[(4 * g + j) * 72      + t * 16 + c];
                vf[4 + j] = vst[(16 + 4 * g + j) * 72 + t * 16 + c];
            }
            accA[t] = MFMA16(pfa, vf, accA[t], 0, 0, 0);
            accB[t] = MFMA16(pfb, vf, accB[t], 0, 0, 0);
        }
    }

    // reduce l across g-groups (m already group-uniform per row)
    lA += __shfl_xor(lA, 16); lA += __shfl_xor(lA, 32);
    lB += __shfl_xor(lB, 16); lB += __shfl_xor(lB, 32);

    // stage partials into OWN region (V stage dead)
    if (g == 0) {
        Lml[c]      = mA;  Lml[16 + c] = mB;
        Lml[32 + c] = lA;  Lml[48 + c] = lB;
    }
    #pragma unroll
    for (int t = 0; t < 4; ++t)
        #pragma unroll
        for (int r = 0; r < 4; ++r) {
            Lacc[(4 * g + r) * 68 + t * 16 + c]      = accA[t][r];
            Lacc[(16 + 4 * g + r) * 68 + t * 16 + c] = accB[t][r];
        }
    __syncthreads();

    // combine: wave w handles d-columns [w*16, w*16+16); lane does 8 rows
    const int col = wave * 16 + c;
    #pragma unroll
    for (int half = 0; half < 2; ++half)
        #pragma unroll
        for (int r = 0; r < 4; ++r) {
            const int row = half * 16 + 4 * g + r;
            float mu[4], lu[4], ou[4], M = -1e30f;
            #pragma unroll
            for (int u = 0; u < 4; ++u) {
                const float* LaccU = (const float*)(smem + u * 9216);
                const float* LmlU  = (const float*)(smem + u * 9216 + 8704);
                mu[u] = LmlU[row];
                lu[u] = LmlU[32 + row];
                ou[u] = LaccU[row * 68 + col];
                M = fmaxf(M, mu[u]);
            }
            float L = 0.f, o = 0.f;
            #pragma unroll
            for (int u = 0; u < 4; ++u) {
                const float w = __builtin_exp2f(mu[u] - M);
                L += w * lu[u];
                o += w * ou[u];
            }
            Ob[(size_t)(b * Sc + q0 + row) * Dc + h * HDc + col] =
                f32_to_bf16_bits(o / L);
        }
}

// ---------------------------------------------------------------------------
extern "C" void kernel_launch(void* const* d_in, const int* in_sizes, int n_in,
                              void* d_out, int out_size, void* d_ws, size_t ws_size,
                              hipStream_t stream) {
    const float* x  = (const float*)d_in[0];
    const int* mask = (const int*)d_in[1];
    const float* Wq = (const float*)d_in[2];
    const float* bq = (const float*)d_in[3];
    const float* Wk = (const float*)d_in[4];
    const float* bk = (const float*)d_in[5];
    const float* Wv = (const float*)d_in[6];
    const float* bv = (const float*)d_in[7];
    const float* Wo = (const float*)d_in[8];
    const float* bo = (const float*)d_in[9];
    float* out = (float*)d_out;   // reference output dtype is float32

    // workspace layout (ushort elems):
    unsigned short* Xb = (unsigned short*)d_ws;          // 2M   (4 MB)
    unsigned short* Wt = Xb + (size_t)Mtot * 512;        // 4x256K (2 MB)
    unsigned short* Qh = Wt + (size_t)4 * 512 * 512;     // 2M  (head-major)
    unsigned short* Kh = Qh + HEADMAT;                   // 2M  (head-major)
    unsigned short* Vh = Kh + HEADMAT;                   // 2M  (head-major)
    unsigned short* Ob = Vh + HEADMAT;                   // 2M
    // total: 18 MB

    convert_x<<<dim3((Mtot * 512) / 1024), dim3(256), 0, stream>>>(
        x, Xb, Mtot * 512);
    transpose_w<<<dim3(8, 8, 4), dim3(256), 0, stream>>>(Wq, Wk, Wv, Wo, Wt);
    gemm_tile<true><<<dim3(8, Mtot / 128, 3), dim3(256), 0, stream>>>(
        Xb, Wt, bq, bk, bv, Qh, nullptr);
    attn_mfma<<<dim3(1024), dim3(256), 0, stream>>>(
        (const short*)Qh, (const short*)Kh, (const short*)Vh, mask, Ob);
    gemm_tile<false><<<dim3(8, Mtot / 128, 1), dim3(256), 0, stream>>>(
        Ob, Wt + (size_t)3 * 512 * 512, bo, bo, bo, nullptr, out);
}

// Round 12
// 107.373 us; speedup vs baseline: 1.0216x; 1.0216x over previous
//
#include <hip/hip_runtime.h>
#include <hip/hip_bf16.h>

// Problem constants (B=2, S=2048, D=512, H=8, hd=64)
constexpr int Bc = 2, Sc = 2048, Dc = 512, Hc = 8, HDc = 64;
constexpr int Mtot = Bc * Sc;    // 4096
constexpr size_t HEADMAT = (size_t)Bc * Hc * Sc * HDc;  // 2M elems
// softmax in log2 domain: e2 = s*(0.125*log2e) - 10000*log2e*masks
constexpr float SC2  = 0.18033688011112042f;   // 0.125 * log2(e)
constexpr float NEG2 = 14426.950408889634f;    // 10000 * log2(e)

typedef __attribute__((ext_vector_type(8))) short          short8;
typedef __attribute__((ext_vector_type(8))) unsigned short ushort8;
typedef __attribute__((ext_vector_type(4))) float          f32x4;

#define MFMA16 __builtin_amdgcn_mfma_f32_16x16x32_bf16

static __device__ __forceinline__ unsigned short f32_to_bf16_bits(float f) {
    unsigned int u = __builtin_bit_cast(unsigned int, f);
    unsigned int r = u + 0x7FFFu + ((u >> 16) & 1u);   // RNE
    return (unsigned short)(r >> 16);
}

// ---------------------------------------------------------------------------
// x f32 -> bf16 (row-major [M][512] unchanged layout)
// ---------------------------------------------------------------------------
__global__ __launch_bounds__(256)
void convert_x(const float* __restrict__ x, unsigned short* __restrict__ Xb, int n)
{
    const int i = (blockIdx.x * 256 + threadIdx.x) * 4;
    if (i >= n) return;
    const float4 v = *(const float4*)(x + i);
    ushort4 o;
    o.x = f32_to_bf16_bits(v.x);
    o.y = f32_to_bf16_bits(v.y);
    o.z = f32_to_bf16_bits(v.z);
    o.w = f32_to_bf16_bits(v.w);
    *(ushort4*)(Xb + i) = o;
}

// ---------------------------------------------------------------------------
// W [512][512] f32 -> W^T [512][512] bf16, z = {Wq,Wk,Wv,Wo}. 64x64 LDS tile.
// ---------------------------------------------------------------------------
__global__ __launch_bounds__(256)
void transpose_w(const float* __restrict__ W0, const float* __restrict__ W1,
                 const float* __restrict__ W2, const float* __restrict__ W3,
                 unsigned short* __restrict__ Wt)
{
    __shared__ float T[64][65];
    const int z = blockIdx.z;
    const float* Wp = (z == 0) ? W0 : (z == 1) ? W1 : (z == 2) ? W2 : W3;
    unsigned short* Op = Wt + (size_t)z * 512 * 512;

    const int kt = blockIdx.y * 64, nt = blockIdx.x * 64;
    const int t = threadIdx.x;
    const int r  = t >> 2, c4 = (t & 3) * 16;

    #pragma unroll
    for (int i = 0; i < 4; ++i) {
        const float4 v = *(const float4*)(Wp + (size_t)(kt + r) * 512 + nt + c4 + 4 * i);
        T[r][c4 + 4*i + 0] = v.x;
        T[r][c4 + 4*i + 1] = v.y;
        T[r][c4 + 4*i + 2] = v.z;
        T[r][c4 + 4*i + 3] = v.w;
    }
    __syncthreads();

    const int n = t >> 2, k4 = (t & 3) * 16;
    #pragma unroll
    for (int i = 0; i < 4; ++i) {
        ushort4 o;
        o.x = f32_to_bf16_bits(T[k4 + 4*i + 0][n]);
        o.y = f32_to_bf16_bits(T[k4 + 4*i + 1][n]);
        o.z = f32_to_bf16_bits(T[k4 + 4*i + 2][n]);
        o.w = f32_to_bf16_bits(T[k4 + 4*i + 3][n]);
        *(ushort4*)(Op + (size_t)(nt + n) * 512 + kt + k4 + 4 * i) = o;
    }
}

// ---------------------------------------------------------------------------
// Tiled bf16 MFMA GEMM (unchanged from R9 -- verified).
// ---------------------------------------------------------------------------
template<bool HEADOUT>
__global__ __launch_bounds__(256)
void gemm_tile(const unsigned short* __restrict__ Xb,
               const unsigned short* __restrict__ Wt,
               const float* __restrict__ b0, const float* __restrict__ b1,
               const float* __restrict__ b2,
               unsigned short* __restrict__ Hout,
               float* __restrict__ Yf)
{
    __shared__ short As[128 * 32];   // [m][k] 8KB
    __shared__ short Bs[64 * 32];    // [n][k] 4KB

    const int lane = threadIdx.x & 63, wave = threadIdx.x >> 6;
    const int c = lane & 15, g = lane >> 4;
    const int wr = wave >> 1, wc = wave & 1;
    const int z = blockIdx.z;
    const unsigned short* Wp = Wt + (size_t)z * 512 * 512;
    const float* bp = (z == 0) ? b0 : (z == 1) ? b1 : b2;
    const int bm = blockIdx.y * 128;
    const int bn = blockIdx.x * 64;

    const int srow = lane >> 2;
    const int scol = (lane & 3) * 8;

    f32x4 acc[4][2] = {};

    for (int k0 = 0; k0 < 512; k0 += 32) {
        __syncthreads();
        #pragma unroll
        for (int i = 0; i < 2; ++i) {
            const int row = (wave * 2 + i) * 16 + srow;
            const short8 v = *(const short8*)(Xb + (size_t)(bm + row) * 512 + k0 + scol);
            *(short8*)(&As[row * 32 + scol]) = v;
        }
        {
            const int row = wave * 16 + srow;
            const short8 v = *(const short8*)(Wp + (size_t)(bn + row) * 512 + k0 + scol);
            *(short8*)(&Bs[row * 32 + scol]) = v;
        }
        __syncthreads();

        short8 a[4], bfr[2];
        #pragma unroll
        for (int mi = 0; mi < 4; ++mi)
            a[mi] = *(const short8*)(&As[(wr * 64 + mi * 16 + c) * 32 + g * 8]);
        #pragma unroll
        for (int ni = 0; ni < 2; ++ni)
            bfr[ni] = *(const short8*)(&Bs[(wc * 32 + ni * 16 + c) * 32 + g * 8]);
        #pragma unroll
        for (int mi = 0; mi < 4; ++mi)
            #pragma unroll
            for (int ni = 0; ni < 2; ++ni)
                acc[mi][ni] = MFMA16(a[mi], bfr[ni], acc[mi][ni], 0, 0, 0);
    }

    #pragma unroll
    for (int mi = 0; mi < 4; ++mi) {
        #pragma unroll
        for (int ni = 0; ni < 2; ++ni) {
            const int n = bn + wc * 32 + ni * 16 + c;
            const float bias = bp[n];
            float v[4];
            #pragma unroll
            for (int r = 0; r < 4; ++r)
                v[r] = fmaxf(acc[mi][ni][r] + bias, 0.0f);
            const int mbase = bm + wr * 64 + mi * 16 + 4 * g;
            if constexpr (HEADOUT) {
                const int bb = mbase >> 11, ss = mbase & 2047;
                const int hh = n >> 6, hd = n & 63;
                #pragma unroll
                for (int r = 0; r < 4; ++r)
                    Hout[(size_t)z * HEADMAT +
                         (((size_t)(bb * Hc + hh) * Sc + ss + r) * HDc + hd)] =
                        f32_to_bf16_bits(v[r]);
            } else {
                #pragma unroll
                for (int r = 0; r < 4; ++r)
                    Yf[(size_t)(mbase + r) * 512 + n] = v[r];
            }
        }
    }
}

// ---------------------------------------------------------------------------
// Split-K MFMA flash attention, v8: MIRROR-PAIRED q-tiles for cross-block
// load balance. Block = 16-row tile p AND tile 127-p of one (b,h):
// kendA + kendB ~ Sc + 32 for EVERY block -> uniform block duration, no tail
// (R7/R9/R11 all pinned at 77us by the kend~2048 tail blocks).
// Each tile runs the R9-verified loop independently (8 MFMA / 32-key iter):
// early V loads -> QK^T -> exp2-softmax w/ defer-rescale -> private-LDS V
// gather -> PV. 4 waves take balanced contiguous chunks within each tile.
// Combine both tiles from the LDS overlay at the end.
// ---------------------------------------------------------------------------
__global__ __launch_bounds__(256)
void attn_mfma(const short* __restrict__ Qh, const short* __restrict__ Kh,
               const short* __restrict__ Vh, const int* __restrict__ mask,
               unsigned short* __restrict__ Ob)
{
    // per-wave 9216B region: loop = V stage [32][72] bf16 (4608B);
    // combine overlay = Lacc[32][68] f32 (8704B) + m/l[64] (256B)
    __shared__ __align__(16) char smem[4 * 9216];

    const int lane = threadIdx.x & 63;
    const int wave = threadIdx.x >> 6;
    const int bid  = blockIdx.x;                    // 1024 blocks
    const int swz  = (bid & 7) * 128 + (bid >> 3);  // bijective, XCD-chunked
    const int p    = swz & 63;                      // pair index 0..63
    const int h    = (swz >> 6) & 7;
    const int b    = swz >> 9;
    const int q0A  = p * 16;                        // small-kend tile
    const int q0B  = (127 - p) * 16;                // mirror (large-kend) tile
    const int c    = lane & 15;
    const int g    = lane >> 4;

    char*  wbase = smem + wave * 9216;
    short* vst   = (short*)wbase;            // [32][72]
    float* Lacc  = (float*)wbase;            // overlay [32][68]
    float* Lml   = (float*)(wbase + 8704);   // overlay mA/mB/lA/lB [16] each

    const size_t headoff = (size_t)(b * Hc + h) * Sc * HDc;
    const short* Qp = Qh + headoff;
    const short* Kp = Kh + headoff;
    const short* Vp = Vh + headoff;
    const int* mb = mask + b * Sc;

    // first unmasked key (block-uniform)
    int fb = Sc;
    for (int base = 0; base < Sc; base += 64) {
        unsigned long long bal = __ballot(mb[base + lane] != 0);
        if (bal) { fb = base + (__ffsll(bal) - 1); break; }
    }

    const int vrow = lane >> 1;            // 0..31
    const int vcol = (lane & 1) * 32;      // 0 or 32

    f32x4 accA[4] = {{0,0,0,0},{0,0,0,0},{0,0,0,0},{0,0,0,0}};
    f32x4 accB[4] = {{0,0,0,0},{0,0,0,0},{0,0,0,0},{0,0,0,0}};
    float mA = -1e30f, lA = 0.f, mB = -1e30f, lB = 0.f;

    // ---- one tile's processing (R9-verified body), macro'd over (A,B) ----
#define TILE_LOOP(q0X, accX, mX, lX, qx0, qx1)                                 \
    {                                                                          \
        const int kmax = (fb <= (q0X)) ? ((q0X) + 16) : Sc;                    \
        const int kend = (kmax + 31) & ~31;                                    \
        const int nT   = kend >> 5;                                            \
        const int tpw  = (nT + 3) >> 2;                                        \
        const int kbeg = wave * tpw * 32;                                      \
        const int kfin = min(kend, kbeg + tpw * 32);                           \
        for (int k0 = kbeg; k0 < kfin; k0 += 32) {                             \
            const short* vsrc = Vp + (size_t)(k0 + vrow) * HDc + vcol;         \
            const ushort8 vr0 = *(const ushort8*)(vsrc + 0);                   \
            const ushort8 vr1 = *(const ushort8*)(vsrc + 8);                   \
            const ushort8 vr2 = *(const ushort8*)(vsrc + 16);                  \
            const ushort8 vr3 = *(const ushort8*)(vsrc + 24);                  \
            const short8 kf0a = *(const short8*)(Kp + (size_t)(k0 + c) * HDc + g * 8);        \
            const short8 kf0b = *(const short8*)(Kp + (size_t)(k0 + c) * HDc + 32 + g * 8);   \
            const short8 kf1a = *(const short8*)(Kp + (size_t)(k0 + 16 + c) * HDc + g * 8);   \
            const short8 kf1b = *(const short8*)(Kp + (size_t)(k0 + 16 + c) * HDc + 32 + g * 8);\
            f32x4 s0 = {0,0,0,0}, s1 = {0,0,0,0};                              \
            s0 = MFMA16(kf0a, qx0, s0, 0, 0, 0);                               \
            s0 = MFMA16(kf0b, qx1, s0, 0, 0, 0);                               \
            s1 = MFMA16(kf1a, qx0, s1, 0, 0, 0);                               \
            s1 = MFMA16(kf1b, qx1, s1, 0, 0, 0);                               \
            const int4 mka = *(const int4*)(mb + k0 + 4 * g);                  \
            const int4 mkb = *(const int4*)(mb + k0 + 16 + 4 * g);             \
            const int mia[4] = {mka.x, mka.y, mka.z, mka.w};                   \
            const int mib[4] = {mkb.x, mkb.y, mkb.z, mkb.w};                   \
            float e[8];                                                        \
            float tmax = -1e30f;                                               \
            if (k0 + 31 > (q0X)) {                                             \
                _Pragma("unroll")                                              \
                for (int r = 0; r < 4; ++r) {                                  \
                    const int ka = k0 + 4 * g + r;                             \
                    const int kb2 = k0 + 16 + 4 * g + r;                       \
                    float e0 = s0[r] * SC2; if (ka  > (q0X) + c) e0 -= NEG2;   \
                    float e1 = s1[r] * SC2; if (kb2 > (q0X) + c) e1 -= NEG2;   \
                    if (mia[r] == 0) e0 -= NEG2;                               \
                    if (mib[r] == 0) e1 -= NEG2;                               \
                    e[r] = e0; e[4 + r] = e1;                                  \
                    tmax = fmaxf(tmax, fmaxf(e0, e1));                         \
                }                                                              \
            } else {                                                           \
                _Pragma("unroll")                                              \
                for (int r = 0; r < 4; ++r) {                                  \
                    float e0 = s0[r] * SC2;                                    \
                    float e1 = s1[r] * SC2;                                    \
                    if (mia[r] == 0) e0 -= NEG2;                               \
                    if (mib[r] == 0) e1 -= NEG2;                               \
                    e[r] = e0; e[4 + r] = e1;                                  \
                    tmax = fmaxf(tmax, fmaxf(e0, e1));                         \
                }                                                              \
            }                                                                  \
            tmax = fmaxf(tmax, __shfl_xor(tmax, 16));                          \
            tmax = fmaxf(tmax, __shfl_xor(tmax, 32));                          \
            if (__any(tmax > (mX))) {                                          \
                const float mn = fmaxf((mX), tmax);                            \
                const float corr = __builtin_exp2f((mX) - mn);                 \
                (mX) = mn; (lX) *= corr;                                       \
                float cq[4];                                                   \
                _Pragma("unroll")                                              \
                for (int r = 0; r < 4; ++r) cq[r] = __shfl(corr, 4 * g + r);   \
                _Pragma("unroll")                                              \
                for (int t = 0; t < 4; ++t)                                    \
                    _Pragma("unroll")                                          \
                    for (int r = 0; r < 4; ++r) (accX)[t][r] *= cq[r];         \
            }                                                                  \
            float pv[8], ps = 0.f;                                             \
            _Pragma("unroll")                                                  \
            for (int j = 0; j < 8; ++j) {                                      \
                pv[j] = __builtin_exp2f(e[j] - (mX)); ps += pv[j];             \
            }                                                                  \
            (lX) += ps;                                                        \
            short8 pf;                                                         \
            _Pragma("unroll")                                                  \
            for (int j = 0; j < 8; ++j) pf[j] = (short)f32_to_bf16_bits(pv[j]);\
            short* vdst = vst + vrow * 72 + vcol;                              \
            *(ushort8*)(vdst + 0)  = vr0;                                      \
            *(ushort8*)(vdst + 8)  = vr1;                                      \
            *(ushort8*)(vdst + 16) = vr2;                                      \
            *(ushort8*)(vdst + 24) = vr3;                                      \
            _Pragma("unroll")                                                  \
            for (int t = 0; t < 4; ++t) {                                      \
                short8 vf;                                                     \
                _Pragma("unroll")                                              \
                for (int j = 0; j < 4; ++j) {                                  \
                    vf[j]     = vst[(4 * g + j) * 72      + t * 16 + c];       \
                    vf[4 + j] = vst[(16 + 4 * g + j) * 72 + t * 16 + c];       \
                }                                                              \
                (accX)[t] = MFMA16(pf, vf, (accX)[t], 0, 0, 0);                \
            }                                                                  \
        }                                                                      \
    }

    {
        const short8 qa0 = *(const short8*)(Qp + (size_t)(q0A + c) * HDc + g * 8);
        const short8 qa1 = *(const short8*)(Qp + (size_t)(q0A + c) * HDc + 32 + g * 8);
        TILE_LOOP(q0A, accA, mA, lA, qa0, qa1)
    }
    {
        const short8 qb0 = *(const short8*)(Qp + (size_t)(q0B + c) * HDc + g * 8);
        const short8 qb1 = *(const short8*)(Qp + (size_t)(q0B + c) * HDc + 32 + g * 8);
        TILE_LOOP(q0B, accB, mB, lB, qb0, qb1)
    }
#undef TILE_LOOP

    // reduce l across g-groups (m already group-uniform per row)
    lA += __shfl_xor(lA, 16); lA += __shfl_xor(lA, 32);
    lB += __shfl_xor(lB, 16); lB += __shfl_xor(lB, 32);

    // stage partials into OWN region (V stage dead)
    if (g == 0) {
        Lml[c]      = mA;  Lml[16 + c] = mB;
        Lml[32 + c] = lA;  Lml[48 + c] = lB;
    }
    #pragma unroll
    for (int t = 0; t < 4; ++t)
        #pragma unroll
        for (int r = 0; r < 4; ++r) {
            Lacc[(4 * g + r) * 68 + t * 16 + c]      = accA[t][r];
            Lacc[(16 + 4 * g + r) * 68 + t * 16 + c] = accB[t][r];
        }
    __syncthreads();

    // combine: wave w handles d-columns [w*16, w*16+16); lane does 8 rows
    const int col = wave * 16 + c;
    #pragma unroll
    for (int half = 0; half < 2; ++half)
        #pragma unroll
        for (int r = 0; r < 4; ++r) {
            const int row = half * 16 + 4 * g + r;     // LDS row
            const int qout = (half ? q0B : q0A) + 4 * g + r;
            float mu[4], lu[4], ou[4], M = -1e30f;
            #pragma unroll
            for (int u = 0; u < 4; ++u) {
                const float* LaccU = (const float*)(smem + u * 9216);
                const float* LmlU  = (const float*)(smem + u * 9216 + 8704);
                mu[u] = LmlU[half * 16 + ((row) & 15)];
                lu[u] = LmlU[32 + half * 16 + ((row) & 15)];
                ou[u] = LaccU[row * 68 + col];
                M = fmaxf(M, mu[u]);
            }
            float L = 0.f, o = 0.f;
            #pragma unroll
            for (int u = 0; u < 4; ++u) {
                const float w = __builtin_exp2f(mu[u] - M);
                L += w * lu[u];
                o += w * ou[u];
            }
            Ob[(size_t)(b * Sc + qout) * Dc + h * HDc + col] =
                f32_to_bf16_bits(o / L);
        }
}

// ---------------------------------------------------------------------------
extern "C" void kernel_launch(void* const* d_in, const int* in_sizes, int n_in,
                              void* d_out, int out_size, void* d_ws, size_t ws_size,
                              hipStream_t stream) {
    const float* x  = (const float*)d_in[0];
    const int* mask = (const int*)d_in[1];
    const float* Wq = (const float*)d_in[2];
    const float* bq = (const float*)d_in[3];
    const float* Wk = (const float*)d_in[4];
    const float* bk = (const float*)d_in[5];
    const float* Wv = (const float*)d_in[6];
    const float* bv = (const float*)d_in[7];
    const float* Wo = (const float*)d_in[8];
    const float* bo = (const float*)d_in[9];
    float* out = (float*)d_out;   // reference output dtype is float32

    // workspace layout (ushort elems):
    unsigned short* Xb = (unsigned short*)d_ws;          // 2M   (4 MB)
    unsigned short* Wt = Xb + (size_t)Mtot * 512;        // 4x256K (2 MB)
    unsigned short* Qh = Wt + (size_t)4 * 512 * 512;     // 2M  (head-major)
    unsigned short* Kh = Qh + HEADMAT;                   // 2M  (head-major)
    unsigned short* Vh = Kh + HEADMAT;                   // 2M  (head-major)
    unsigned short* Ob = Vh + HEADMAT;                   // 2M
    // total: 18 MB

    convert_x<<<dim3((Mtot * 512) / 1024), dim3(256), 0, stream>>>(
        x, Xb, Mtot * 512);
    transpose_w<<<dim3(8, 8, 4), dim3(256), 0, stream>>>(Wq, Wk, Wv, Wo, Wt);
    gemm_tile<true><<<dim3(8, Mtot / 128, 3), dim3(256), 0, stream>>>(
        Xb, Wt, bq, bk, bv, Qh, nullptr);
    attn_mfma<<<dim3(1024), dim3(256), 0, stream>>>(
        (const short*)Qh, (const short*)Kh, (const short*)Vh, mask, Ob);
    gemm_tile<false><<<dim3(8, Mtot / 128, 1), dim3(256), 0, stream>>>(
        Ob, Wt + (size_t)3 * 512 * 512, bo, bo, bo, nullptr, out);
}

// Round 13
// 95.977 us; speedup vs baseline: 1.1429x; 1.1187x over previous
//
#include <hip/hip_runtime.h>
#include <hip/hip_bf16.h>

// Problem constants (B=2, S=2048, D=512, H=8, hd=64)
constexpr int Bc = 2, Sc = 2048, Dc = 512, Hc = 8, HDc = 64;
constexpr int Mtot = Bc * Sc;    // 4096
constexpr size_t HEADMAT = (size_t)Bc * Hc * Sc * HDc;  // 2M elems
// softmax in log2 domain
constexpr float SC2  = 0.18033688011112042f;   // 0.125 * log2(e)
constexpr float NEG2 = 14426.950408889634f;    // 10000 * log2(e)

typedef __attribute__((ext_vector_type(8)))  short          short8;
typedef __attribute__((ext_vector_type(8)))  unsigned short ushort8;
typedef __attribute__((ext_vector_type(4)))  float          f32x4;
typedef __attribute__((ext_vector_type(16))) float          f32x16;

#define MFMA16 __builtin_amdgcn_mfma_f32_16x16x32_bf16
#define MFMA32 __builtin_amdgcn_mfma_f32_32x32x16_bf16

static __device__ __forceinline__ unsigned short f32_to_bf16_bits(float f) {
    unsigned int u = __builtin_bit_cast(unsigned int, f);
    unsigned int r = u + 0x7FFFu + ((u >> 16) & 1u);   // RNE
    return (unsigned short)(r >> 16);
}
static __device__ __forceinline__ unsigned int pkbf(float a, float b) {
    return (unsigned int)f32_to_bf16_bits(a) |
           ((unsigned int)f32_to_bf16_bits(b) << 16);
}

// ---------------------------------------------------------------------------
// x f32 -> bf16
// ---------------------------------------------------------------------------
__global__ __launch_bounds__(256)
void convert_x(const float* __restrict__ x, unsigned short* __restrict__ Xb, int n)
{
    const int i = (blockIdx.x * 256 + threadIdx.x) * 4;
    if (i >= n) return;
    const float4 v = *(const float4*)(x + i);
    ushort4 o;
    o.x = f32_to_bf16_bits(v.x);
    o.y = f32_to_bf16_bits(v.y);
    o.z = f32_to_bf16_bits(v.z);
    o.w = f32_to_bf16_bits(v.w);
    *(ushort4*)(Xb + i) = o;
}

// ---------------------------------------------------------------------------
// W -> W^T bf16
// ---------------------------------------------------------------------------
__global__ __launch_bounds__(256)
void transpose_w(const float* __restrict__ W0, const float* __restrict__ W1,
                 const float* __restrict__ W2, const float* __restrict__ W3,
                 unsigned short* __restrict__ Wt)
{
    __shared__ float T[64][65];
    const int z = blockIdx.z;
    const float* Wp = (z == 0) ? W0 : (z == 1) ? W1 : (z == 2) ? W2 : W3;
    unsigned short* Op = Wt + (size_t)z * 512 * 512;

    const int kt = blockIdx.y * 64, nt = blockIdx.x * 64;
    const int t = threadIdx.x;
    const int r  = t >> 2, c4 = (t & 3) * 16;

    #pragma unroll
    for (int i = 0; i < 4; ++i) {
        const float4 v = *(const float4*)(Wp + (size_t)(kt + r) * 512 + nt + c4 + 4 * i);
        T[r][c4 + 4*i + 0] = v.x;
        T[r][c4 + 4*i + 1] = v.y;
        T[r][c4 + 4*i + 2] = v.z;
        T[r][c4 + 4*i + 3] = v.w;
    }
    __syncthreads();

    const int n = t >> 2, k4 = (t & 3) * 16;
    #pragma unroll
    for (int i = 0; i < 4; ++i) {
        ushort4 o;
        o.x = f32_to_bf16_bits(T[k4 + 4*i + 0][n]);
        o.y = f32_to_bf16_bits(T[k4 + 4*i + 1][n]);
        o.z = f32_to_bf16_bits(T[k4 + 4*i + 2][n]);
        o.w = f32_to_bf16_bits(T[k4 + 4*i + 3][n]);
        *(ushort4*)(Op + (size_t)(nt + n) * 512 + kt + k4 + 4 * i) = o;
    }
}

// ---------------------------------------------------------------------------
// Tiled bf16 MFMA GEMM (unchanged, verified R9-R12).
// ---------------------------------------------------------------------------
template<bool HEADOUT>
__global__ __launch_bounds__(256)
void gemm_tile(const unsigned short* __restrict__ Xb,
               const unsigned short* __restrict__ Wt,
               const float* __restrict__ b0, const float* __restrict__ b1,
               const float* __restrict__ b2,
               unsigned short* __restrict__ Hout,
               float* __restrict__ Yf)
{
    __shared__ short As[128 * 32];
    __shared__ short Bs[64 * 32];

    const int lane = threadIdx.x & 63, wave = threadIdx.x >> 6;
    const int c = lane & 15, g = lane >> 4;
    const int wr = wave >> 1, wc = wave & 1;
    const int z = blockIdx.z;
    const unsigned short* Wp = Wt + (size_t)z * 512 * 512;
    const float* bp = (z == 0) ? b0 : (z == 1) ? b1 : b2;
    const int bm = blockIdx.y * 128;
    const int bn = blockIdx.x * 64;

    const int srow = lane >> 2;
    const int scol = (lane & 3) * 8;

    f32x4 acc[4][2] = {};

    for (int k0 = 0; k0 < 512; k0 += 32) {
        __syncthreads();
        #pragma unroll
        for (int i = 0; i < 2; ++i) {
            const int row = (wave * 2 + i) * 16 + srow;
            const short8 v = *(const short8*)(Xb + (size_t)(bm + row) * 512 + k0 + scol);
            *(short8*)(&As[row * 32 + scol]) = v;
        }
        {
            const int row = wave * 16 + srow;
            const short8 v = *(const short8*)(Wp + (size_t)(bn + row) * 512 + k0 + scol);
            *(short8*)(&Bs[row * 32 + scol]) = v;
        }
        __syncthreads();

        short8 a[4], bfr[2];
        #pragma unroll
        for (int mi = 0; mi < 4; ++mi)
            a[mi] = *(const short8*)(&As[(wr * 64 + mi * 16 + c) * 32 + g * 8]);
        #pragma unroll
        for (int ni = 0; ni < 2; ++ni)
            bfr[ni] = *(const short8*)(&Bs[(wc * 32 + ni * 16 + c) * 32 + g * 8]);
        #pragma unroll
        for (int mi = 0; mi < 4; ++mi)
            #pragma unroll
            for (int ni = 0; ni < 2; ++ni)
                acc[mi][ni] = MFMA16(a[mi], bfr[ni], acc[mi][ni], 0, 0, 0);
    }

    #pragma unroll
    for (int mi = 0; mi < 4; ++mi) {
        #pragma unroll
        for (int ni = 0; ni < 2; ++ni) {
            const int n = bn + wc * 32 + ni * 16 + c;
            const float bias = bp[n];
            float v[4];
            #pragma unroll
            for (int r = 0; r < 4; ++r)
                v[r] = fmaxf(acc[mi][ni][r] + bias, 0.0f);
            const int mbase = bm + wr * 64 + mi * 16 + 4 * g;
            if constexpr (HEADOUT) {
                const int bb = mbase >> 11, ss = mbase & 2047;
                const int hh = n >> 6, hd = n & 63;
                #pragma unroll
                for (int r = 0; r < 4; ++r)
                    Hout[(size_t)z * HEADMAT +
                         (((size_t)(bb * Hc + hh) * Sc + ss + r) * HDc + hd)] =
                        f32_to_bf16_bits(v[r]);
            } else {
                #pragma unroll
                for (int r = 0; r < 4; ++r)
                    Yf[(size_t)(mbase + r) * 512 + n] = v[r];
            }
        }
    }
}

// ---------------------------------------------------------------------------
// Split-K flash attention, v9: 32x32 MFMA, swapped QK, in-lane softmax.
// Block = ONE 32-row q-tile of one (b,h), 4 waves split the key range.
// QK^T: S = sum_j mfma32(K_j, Q_j): S[key=(r&3)+8(r>>2)+4hi][q=lane&31].
// Softmax: 16 keys in-lane + 1 shfl_xor(32) for the cross-half max/sum.
// P->B-operand exchange: packed bf16 pairs + shfl_xor(32) + cndmask
// (derivation: frag f keyset [16f,16f+16), slot 8hi+e -> key 16f+8hi+e;
//  w0=hi?C's:A, w1=hi?D's:B, w2=hi?C:A's, w3=hi?D:B's, X'=shfl_xor(X,32)).
// PV: O^T = mfma32(V^T_frag, P_frag): q stays lane-local -> rescale and
// combine weights are per-lane scalars (no broadcasts).
// V staged to wave-private LDS [32][72]; combine partials in LDS overlay.
// ---------------------------------------------------------------------------
__global__ __launch_bounds__(256)
void attn_mfma(const short* __restrict__ Qh, const short* __restrict__ Kh,
               const short* __restrict__ Vh, const int* __restrict__ mask,
               unsigned short* __restrict__ Ob)
{
    // per-wave 8448B region: loop = V stage [32][72] bf16 (4608B used);
    // overlay after loop = Lacc[64][33] f32 (8448B). Lml separate 256B/wave.
    __shared__ __align__(16) char smem[4 * 8448 + 4 * 256];

    const int lane = threadIdx.x & 63;
    const int wave = threadIdx.x >> 6;
    const int bid  = blockIdx.x;                    // 1024 blocks
    const int swz  = (bid & 7) * 128 + (bid >> 3);  // XCD-chunked, bijective
    const int t    = swz & 63;
    const int h    = (swz >> 6) & 7;
    const int b    = swz >> 9;
    const int q0   = t * 32;
    const int r32  = lane & 31;
    const int hi   = lane >> 5;

    char*  wreg = smem + wave * 8448;
    short* vst  = (short*)wreg;                       // [32][72]
    float* Lml  = (float*)(smem + 4 * 8448 + wave * 256);

    const size_t headoff = (size_t)(b * Hc + h) * Sc * HDc;
    const short* Qp = Qh + headoff;
    const short* Kp = Kh + headoff;
    const short* Vp = Vh + headoff;
    const int* mb = mask + b * Sc;

    // first unmasked key (block-uniform)
    int fb = Sc;
    for (int base = 0; base < Sc; base += 64) {
        unsigned long long bal = __ballot(mb[base + lane] != 0);
        if (bal) { fb = base + (__ffsll(bal) - 1); break; }
    }
    const int kmax = (fb <= q0) ? (q0 + 32) : Sc;
    const int kend = (kmax + 31) & ~31;
    const int nT   = kend >> 5;
    const int tpw  = (nT + 3) >> 2;
    const int kbeg = wave * tpw * 32;
    const int kfin = min(kend, kbeg + tpw * 32);

    // Q fragments (B-operand): Q[q=r32][d = 16j + 8hi + e]
    short8 qf[4];
    #pragma unroll
    for (int j = 0; j < 4; ++j)
        qf[j] = *(const short8*)(Qp + (size_t)(q0 + r32) * HDc + j * 16 + hi * 8);

    f32x16 acc0 = {0,0,0,0,0,0,0,0,0,0,0,0,0,0,0,0};
    f32x16 acc1 = {0,0,0,0,0,0,0,0,0,0,0,0,0,0,0,0};
    float m = -1e30f, l = 0.0f;

    const int vrow = lane >> 1, vcol = (lane & 1) * 32;

    for (int k0 = kbeg; k0 < kfin; k0 += 32) {
        // --- V stage loads issued early
        const short* vsrc = Vp + (size_t)(k0 + vrow) * HDc + vcol;
        const ushort8 vr0 = *(const ushort8*)(vsrc + 0);
        const ushort8 vr1 = *(const ushort8*)(vsrc + 8);
        const ushort8 vr2 = *(const ushort8*)(vsrc + 16);
        const ushort8 vr3 = *(const ushort8*)(vsrc + 24);

        // --- K fragments (A-operand): K[key=r32][d = 16j + 8hi + e]
        f32x16 s = {0,0,0,0,0,0,0,0,0,0,0,0,0,0,0,0};
        #pragma unroll
        for (int j = 0; j < 4; ++j) {
            const short8 kf =
                *(const short8*)(Kp + (size_t)(k0 + r32) * HDc + j * 16 + hi * 8);
            s = MFMA32(kf, qf[j], s, 0, 0, 0);
        }

        // --- padding-mask bits (wave-uniform 32-bit word via ballot)
        const unsigned long long bal = __ballot(mb[k0 + r32] != 0);
        const unsigned int mloc = ((unsigned int)bal) >> (4 * hi);

        float e[16];
        float tmax = -1e30f;
        if (k0 + 31 > q0) {   // diagonal tile: causal compares needed
            #pragma unroll
            for (int r = 0; r < 16; ++r) {
                const int cr0 = (r & 3) + 8 * (r >> 2);
                float ev = s[r] * SC2;
                if (!((mloc >> cr0) & 1))            ev -= NEG2;
                if (k0 + cr0 + 4 * hi > q0 + r32)    ev -= NEG2;
                e[r] = ev;
                tmax = fmaxf(tmax, ev);
            }
        } else {
            #pragma unroll
            for (int r = 0; r < 16; ++r) {
                const int cr0 = (r & 3) + 8 * (r >> 2);
                float ev = s[r] * SC2;
                if (!((mloc >> cr0) & 1))            ev -= NEG2;
                e[r] = ev;
                tmax = fmaxf(tmax, ev);
            }
        }
        tmax = fmaxf(tmax, __shfl_xor(tmax, 32));   // full-row max

        if (__any(tmax > m)) {
            const float mn   = fmaxf(m, tmax);
            const float corr = __builtin_exp2f(m - mn);
            m = mn; l *= corr;
            acc0 *= corr;            // q = lane&31: rescale is lane-local
            acc1 *= corr;
        }

        float ps = 0.f;
        #pragma unroll
        for (int r = 0; r < 16; ++r) {
            e[r] = __builtin_exp2f(e[r] - m);   // e[] now holds p
            ps += e[r];
        }
        l += ps;   // own-half partial; cross-half summed at the end

        // --- pack P pairs and exchange across lane-halves
        const unsigned int A0 = pkbf(e[0],  e[1]),  B0 = pkbf(e[2],  e[3]);
        const unsigned int C0 = pkbf(e[4],  e[5]),  D0 = pkbf(e[6],  e[7]);
        const unsigned int A1 = pkbf(e[8],  e[9]),  B1 = pkbf(e[10], e[11]);
        const unsigned int C1 = pkbf(e[12], e[13]), D1 = pkbf(e[14], e[15]);
        const unsigned int A0s = (unsigned int)__shfl_xor((int)A0, 32);
        const unsigned int B0s = (unsigned int)__shfl_xor((int)B0, 32);
        const unsigned int C0s = (unsigned int)__shfl_xor((int)C0, 32);
        const unsigned int D0s = (unsigned int)__shfl_xor((int)D0, 32);
        const unsigned int A1s = (unsigned int)__shfl_xor((int)A1, 32);
        const unsigned int B1s = (unsigned int)__shfl_xor((int)B1, 32);
        const unsigned int C1s = (unsigned int)__shfl_xor((int)C1, 32);
        const unsigned int D1s = (unsigned int)__shfl_xor((int)D1, 32);

        union { unsigned int u[4]; short8 s8; } P0, P1;
        P0.u[0] = hi ? C0s : A0;  P0.u[1] = hi ? D0s : B0;
        P0.u[2] = hi ? C0  : A0s; P0.u[3] = hi ? D0  : B0s;
        P1.u[0] = hi ? C1s : A1;  P1.u[1] = hi ? D1s : B1;
        P1.u[2] = hi ? C1  : A1s; P1.u[3] = hi ? D1  : B1s;

        // --- V regs -> wave-private LDS
        short* vdst = vst + vrow * 72 + vcol;
        *(ushort8*)(vdst + 0)  = vr0;
        *(ushort8*)(vdst + 8)  = vr1;
        *(ushort8*)(vdst + 16) = vr2;
        *(ushort8*)(vdst + 24) = vr3;

        // --- PV: O^T += V^T_frag x P_frag (A-row = d, B-col = q)
        short8 va;
        #pragma unroll
        for (int e8 = 0; e8 < 8; ++e8)
            va[e8] = vst[(8 * hi + e8) * 72 + r32];
        acc0 = MFMA32(va, P0.s8, acc0, 0, 0, 0);
        #pragma unroll
        for (int e8 = 0; e8 < 8; ++e8)
            va[e8] = vst[(16 + 8 * hi + e8) * 72 + r32];
        acc0 = MFMA32(va, P1.s8, acc0, 0, 0, 0);
        #pragma unroll
        for (int e8 = 0; e8 < 8; ++e8)
            va[e8] = vst[(8 * hi + e8) * 72 + 32 + r32];
        acc1 = MFMA32(va, P0.s8, acc1, 0, 0, 0);
        #pragma unroll
        for (int e8 = 0; e8 < 8; ++e8)
            va[e8] = vst[(16 + 8 * hi + e8) * 72 + 32 + r32];
        acc1 = MFMA32(va, P1.s8, acc1, 0, 0, 0);
    }

    l += __shfl_xor(l, 32);   // full-row denominator partial for this wave

    // dump partials into OWN overlay region (V stage dead)
    {
        float* Lacc = (float*)wreg;   // [64][33]
        #pragma unroll
        for (int r = 0; r < 16; ++r) {
            Lacc[lane * 33 + r]      = acc0[r];
            Lacc[lane * 33 + 16 + r] = acc1[r];
        }
        if (lane < 32) { Lml[lane] = m; Lml[32 + lane] = l; }
    }
    __syncthreads();

    // combine: weights per-lane (q = r32); wave w handles acc regs [8w, 8w+8)
    float mu[4], lu[4], M = -1e30f;
    #pragma unroll
    for (int u = 0; u < 4; ++u) {
        const float* LmlU = (const float*)(smem + 4 * 8448 + u * 256);
        mu[u] = LmlU[r32];
        lu[u] = LmlU[32 + r32];
        M = fmaxf(M, mu[u]);
    }
    float wgt[4], L = 0.f;
    #pragma unroll
    for (int u = 0; u < 4; ++u) {
        wgt[u] = __builtin_exp2f(mu[u] - M);
        L += wgt[u] * lu[u];
    }
    const float invL = 1.0f / L;

    #pragma unroll
    for (int jj = 0; jj < 8; ++jj) {
        const int j = wave * 8 + jj;
        float o = 0.f;
        #pragma unroll
        for (int u = 0; u < 4; ++u)
            o += wgt[u] * ((const float*)(smem + u * 8448))[lane * 33 + j];
        const int j16 = j & 15;
        const int d = (j16 & 3) + 8 * (j16 >> 2) + 4 * hi + 32 * (j >> 4);
        Ob[(size_t)(b * Sc + q0 + r32) * Dc + h * HDc + d] =
            f32_to_bf16_bits(o * invL);
    }
}

// ---------------------------------------------------------------------------
extern "C" void kernel_launch(void* const* d_in, const int* in_sizes, int n_in,
                              void* d_out, int out_size, void* d_ws, size_t ws_size,
                              hipStream_t stream) {
    const float* x  = (const float*)d_in[0];
    const int* mask = (const int*)d_in[1];
    const float* Wq = (const float*)d_in[2];
    const float* bq = (const float*)d_in[3];
    const float* Wk = (const float*)d_in[4];
    const float* bk = (const float*)d_in[5];
    const float* Wv = (const float*)d_in[6];
    const float* bv = (const float*)d_in[7];
    const float* Wo = (const float*)d_in[8];
    const float* bo = (const float*)d_in[9];
    float* out = (float*)d_out;   // reference output dtype is float32

    unsigned short* Xb = (unsigned short*)d_ws;          // 4 MB
    unsigned short* Wt = Xb + (size_t)Mtot * 512;        // 2 MB
    unsigned short* Qh = Wt + (size_t)4 * 512 * 512;     // head-major
    unsigned short* Kh = Qh + HEADMAT;
    unsigned short* Vh = Kh + HEADMAT;
    unsigned short* Ob = Vh + HEADMAT;

    convert_x<<<dim3((Mtot * 512) / 1024), dim3(256), 0, stream>>>(
        x, Xb, Mtot * 512);
    transpose_w<<<dim3(8, 8, 4), dim3(256), 0, stream>>>(Wq, Wk, Wv, Wo, Wt);
    gemm_tile<true><<<dim3(8, Mtot / 128, 3), dim3(256), 0, stream>>>(
        Xb, Wt, bq, bk, bv, Qh, nullptr);
    attn_mfma<<<dim3(1024), dim3(256), 0, stream>>>(
        (const short*)Qh, (const short*)Kh, (const short*)Vh, mask, Ob);
    gemm_tile<false><<<dim3(8, Mtot / 128, 1), dim3(256), 0, stream>>>(
        Ob, Wt + (size_t)3 * 512 * 512, bo, bo, bo, nullptr, out);
}